// Round 10
// baseline (218.672 us; speedup 1.0000x reference)
//
#include <hip/hip_runtime.h>

#define ACT 14
#define CC 128
#define HH 256
#define EPB 182                 // edges per batch (14*13)
#define NB 2048
#define M2 (NB*EPB)             // 372736 edge-rows
#define NS 520                  // nodeL stride in shorts
#define LP_CONST (-182.0f * 0.91893853320467274f)   // -E*0.5*ln(2pi)

typedef short s16x8 __attribute__((ext_vector_type(8)));
typedef _Float16 h16x8 __attribute__((ext_vector_type(8)));
typedef _Float16 h16x2 __attribute__((ext_vector_type(2)));
typedef float f32x2 __attribute__((ext_vector_type(2)));
typedef float f32x4 __attribute__((ext_vector_type(4)));
typedef int   i32x4 __attribute__((ext_vector_type(4)));
typedef float f32x16 __attribute__((ext_vector_type(16)));

__device__ __forceinline__ float softplusf(float x) { return x > 15.f ? x : log1pf(expf(x)); }
__device__ __forceinline__ float leaky(float x) { return fmaxf(x, 0.01f * x); }

__device__ __forceinline__ short f2bf(float f) {
    unsigned u = __float_as_uint(f);
    unsigned r = (u + 0x7fffu + ((u >> 16) & 1u)) >> 16;   // RNE
    return (short)r;
}
__device__ __forceinline__ float bflo(int m) { return __uint_as_float(((unsigned)m) << 16); }
__device__ __forceinline__ float bfhi(int m) { return __uint_as_float((unsigned)m & 0xffff0000u); }

__device__ __forceinline__ short f2h(float f) {          // scalar f16, RNE
    _Float16 h = (_Float16)f;
    return __builtin_bit_cast(short, h);
}
__device__ __forceinline__ int pk_f16(float a, float b) { // packed f16, RTZ (1 instr)
    return __builtin_bit_cast(int, __builtin_amdgcn_cvt_pkrtz(a, b));
}
__device__ __forceinline__ int pk_f16_rn(float a, float b) {
    return (int)(unsigned short)f2h(a) | ((int)f2h(b) << 16);
}
__device__ __forceinline__ float fdot2i(int a, int b, float c) {
#if __has_builtin(__builtin_amdgcn_fdot2)
    return __builtin_amdgcn_fdot2(__builtin_bit_cast(h16x2, a),
                                  __builtin_bit_cast(h16x2, b), c, false);
#else
    h16x2 av = __builtin_bit_cast(h16x2, a), bv = __builtin_bit_cast(h16x2, b);
    return c + (float)av[0] * (float)bv[0] + (float)av[1] * (float)bv[1];
#endif
}

// ---------------------------------------------------------------------------
// prep: one-time weight conversions (256 blocks x 256), fp16 tables.
// ---------------------------------------------------------------------------
__global__ __launch_bounds__(256) void prep_kernel(
    const float* __restrict__ conv_w, const float* __restrict__ lin1_w,
    const float* __restrict__ lin2_w, const float* __restrict__ mu_w,
    const float* __restrict__ sig_w,
    short* __restrict__ W2h, short* __restrict__ W1h,
    int* __restrict__ cwPT, int* __restrict__ w1sPT,
    int* __restrict__ msbf)
{
    int i = blockIdx.x * 256 + threadIdx.x;
    W2h[i] = f2h(lin2_w[i]);
    {
        int n = i >> 7, k = i & 127;
        float v = (n < 256) ? lin1_w[n * 256 + k] : lin1_w[(n - 256) * 256 + 128 + k];
        W1h[i] = f2h(v);
    }
    if (i < 8192) {                     // cwPT[j][p]
        int j = i >> 6, p = i & 63;
        cwPT[i] = pk_f16_rn(conv_w[j * 128 + 2 * p], conv_w[j * 128 + 2 * p + 1]);
    }
    if (i < 16384) {                    // w1sPT[h][p]
        int h = i >> 6, p = i & 63;
        float a0 = lin1_w[h * 256 + 2 * p]     + lin1_w[h * 256 + 128 + 2 * p];
        float a1 = lin1_w[h * 256 + 2 * p + 1] + lin1_w[h * 256 + 128 + 2 * p + 1];
        w1sPT[i] = pk_f16_rn(a0, a1);
    }
    if (i < 256) msbf[i] = (int)(unsigned short)f2bf(mu_w[i]) | ((int)f2bf(sig_w[i]) << 16);
}

// ---------------------------------------------------------------------------
// actor: TWO batches per block (1024 blocks), 512 threads = 8 waves.
//  A : stage state f16 (aliased into h1L); ssum -> packed pairs; LDS tables.
//  A2: g via fdot2 row streams + shfl; w via fdot2 row streams.
//  B : node GEMM -> nodeL[2], 16x16x32 f16 MFMA; wa (W2 strip) hoisted.
//  C : cooperative double-buffered H1 build (R8 frag-order layout,
//      conflict-clean), 32x32x16 f16 MFMA with TWO independent 8-deep
//      accumulator chains (halves exposed dep latency), setprio around
//      the MFMA cluster, packed-bf16 mu/sig epilogue, split atomics.
// ---------------------------------------------------------------------------
__global__ __launch_bounds__(512, 4) void actor_kernel(
    const float* __restrict__ state, const short* __restrict__ W1h,
    const short* __restrict__ W2h,
    const int* __restrict__ cwPT, const float* __restrict__ conv_b,
    const int* __restrict__ w1sPT, const float* __restrict__ lin1_b,
    const float* __restrict__ lin2_b, const int* __restrict__ msbf,
    const float* __restrict__ mu_b, const float* __restrict__ sig_b,
    const float* __restrict__ noise, const int* __restrict__ edges,
    float* __restrict__ out)
{
    __shared__ short h1L[2][8192];           // 32 KB; [0] front aliased below
    __shared__ short nodeL[2 * ACT * NS];    // 29120 B
    __shared__ int   ssP[2][64];             // packed ssum f16 pairs
    __shared__ int   gP[2][64];              // packed g f16 pairs
    __shared__ float wL[2][256];
    __shared__ float b2L[256];               // lin2_b (f32)
    __shared__ int   msL[256];               // packed (mu,sig) bf16 pairs
    __shared__ int2  edgeL[192];             // edge pairs (182 used)
    __shared__ float mu_acc[384], sg_acc[384];
    __shared__ float lp_acc[2];

    short* stateL = &h1L[0][0];              // 2*2560 shorts (dead before build)

    const int t = threadIdx.x, b = blockIdx.x;
    const int lane = t & 63, ln = lane & 15, q = lane >> 4;
    const int w = t >> 6;                     // wave 0..7
    const int l32 = lane & 31, hf = lane >> 5;

    // ---- phase A ----
    #pragma unroll
    for (int it = 0; it < 2; ++it) {
        int idx = it * 512 + t;
        int bt = idx >> 9, row = (idx >> 5) & 15, c4 = idx & 31;
        int kk = c4 >> 3, k8 = (c4 & 7) * 4;
        int* dst = (int*)&stateL[bt * 2560 + kk * 640 + row * 40 + k8];
        if (row < ACT) {
            f32x4 x = *(const f32x4*)(state + ((size_t)(2 * b + bt) * ACT + row) * CC + c4 * 4);
            dst[0] = pk_f16(x[0], x[1]); dst[1] = pk_f16(x[2], x[3]);
        } else { dst[0] = 0; dst[1] = 0; }
    }
    if (t < 256) {
        b2L[t] = lin2_b[t];
        msL[t] = msbf[t];
    } else {
        int i = t - 256, bt = i >> 7, c = i & 127;    // ssum, both batches
        const float* sp = state + (size_t)(2 * b + bt) * ACT * CC + c;
        float s = 0.f;
        #pragma unroll
        for (int r = 0; r < ACT; ++r) s += sp[r * CC];
        s *= (1.f / 14.f);
        float s2 = __shfl_xor(s, 1);          // partner channel (pairs in-wave)
        if (!(c & 1)) ssP[bt][c >> 1] = pk_f16(s, s2);
    }
    if (t < EPB) edgeL[t] = ((const int2*)edges)[t];
    if (t < 384) { mu_acc[t] = 0.f; sg_acc[t] = 0.f; }
    if (t < 2) lp_acc[t] = 0.f;
    __syncthreads();

    // ---- phase A2: g = relu(conv_w @ ssum + b), fdot2 row streams ----
    {
        int bt = t >> 8, r = t & 255, j = r >> 1, s = r & 1;
        const i32x4* wp = (const i32x4*)&cwPT[j * 64 + s * 32];
        const i32x4* sp4 = (const i32x4*)&ssP[bt][s * 32];
        float a0 = 0.f, a1 = 0.f, a2 = 0.f, a3 = 0.f;
        #pragma unroll
        for (int u = 0; u < 8; ++u) {
            i32x4 wv = wp[u]; i32x4 sv = sp4[u];
            a0 = fdot2i(wv[0], sv[0], a0); a1 = fdot2i(wv[1], sv[1], a1);
            a2 = fdot2i(wv[2], sv[2], a2); a3 = fdot2i(wv[3], sv[3], a3);
        }
        float a = (a0 + a1) + (a2 + a3);
        a += __shfl_xor(a, 1);                // combine k-split halves
        float gf = fmaxf(a + conv_b[j], 0.f);
        float go = __shfl_xor(gf, 2);         // neighbor j^1
        if ((r & 3) == 0) gP[bt][r >> 2] = pk_f16(gf, go);
    }
    __syncthreads();
    // ---- w = w1s @ g + lin1_b, fdot2 row streams ----
    {
        int bt = t >> 8, h = t & 255;
        const i32x4* wp = (const i32x4*)&w1sPT[h * 64];
        const i32x4* gp4 = (const i32x4*)&gP[bt][0];
        float a0 = 0.f, a1 = 0.f, a2 = 0.f, a3 = 0.f;
        #pragma unroll 8
        for (int u = 0; u < 16; ++u) {
            i32x4 wv = wp[u]; i32x4 gv = gp4[u];
            a0 = fdot2i(wv[0], gv[0], a0); a1 = fdot2i(wv[1], gv[1], a1);
            a2 = fdot2i(wv[2], gv[2], a2); a3 = fdot2i(wv[3], gv[3], a3);
        }
        wL[bt][h] = (a0 + a1) + (a2 + a3) + lin1_b[h];
    }
    __syncthreads();

    // ---- phase B: node GEMM (u = W1L@x + w | v = W1R@x), both batches ----
    f32x4 zero4 = {0.f, 0.f, 0.f, 0.f};
    f32x4 nacc[2][4];
    #pragma unroll
    for (int bt = 0; bt < 2; ++bt) {
        nacc[bt][0] = zero4; nacc[bt][1] = zero4;
        nacc[bt][2] = zero4; nacc[bt][3] = zero4;
    }
    #pragma unroll
    for (int c = 0; c < 4; ++c) {
        h16x8 a80 = __builtin_bit_cast(h16x8, *(const s16x8*)&stateL[0 * 2560 + c * 640 + ln * 40 + q * 8]);
        h16x8 a81 = __builtin_bit_cast(h16x8, *(const s16x8*)&stateL[1 * 2560 + c * 640 + ln * 40 + q * 8]);
        #pragma unroll
        for (int i = 0; i < 4; ++i) {
            int ct = w + 8 * i;               // 0..31
            h16x8 b8 = __builtin_bit_cast(h16x8, *(const s16x8*)&W1h[(size_t)(ct * 16 + ln) * CC + c * 32 + q * 8]);
            nacc[0][i] = __builtin_amdgcn_mfma_f32_16x16x32_f16(a80, b8, nacc[0][i], 0, 0, 0);
            nacc[1][i] = __builtin_amdgcn_mfma_f32_16x16x32_f16(a81, b8, nacc[1][i], 0, 0, 0);
        }
    }

    // ---- W2 strip loads issued HERE: latency hidden by nodeL writes+barrier
    s16x8 wa[16];
    #pragma unroll
    for (int c = 0; c < 16; ++c)
        wa[c] = *(const s16x8*)&W2h[(size_t)(w * 32 + l32) * HH + c * 16 + hf * 8];

    #pragma unroll
    for (int bt = 0; bt < 2; ++bt)
        #pragma unroll
        for (int i = 0; i < 4; ++i) {
            int col = (w + 8 * i) * 16 + ln;
            float wadd = (col < HH) ? wL[bt][col] : 0.f;
            #pragma unroll
            for (int rg = 0; rg < 4; ++rg) {
                int node = q * 4 + rg;
                if (node < ACT) nodeL[(bt * ACT + node) * NS + col] = f2h(nacc[bt][i][rg] + wadd);
            }
        }
    __syncthreads();   // nodeL visible; stateL now dead

    // cooperative H1 build (each element computed once), frag-order layout,
    // packed fp16 math: 3 VALU per 2 elements; edge pairs from LDS.
    const h16x2 c001 = {(_Float16)0.01f, (_Float16)0.01f};
    auto build = [&](int tile, int bufi) {
        int bt = (tile >= 6) ? 1 : 0;
        int e32 = t & 31;
        int e = (tile - bt * 6) * 32 + e32;
        bool ok = e < EPB;
        int2 p = edgeL[ok ? e : 0];
        int base = bt * ACT * NS;
        int uo = base + p.x * NS, vo = base + HH + p.y * NS;
        int sl = t >> 5;                       // 0..15
        #pragma unroll
        for (int s = 0; s < 2; ++s) {
            int slot = sl + 16 * s;            // 0..31
            int chunk = slot >> 1, half = slot & 1;
            int koff = chunk * 16 + half * 8;
            int o[4] = {0, 0, 0, 0};
            if (ok) {
                s16x8 u8 = *(const s16x8*)&nodeL[uo + koff];
                s16x8 v8 = *(const s16x8*)&nodeL[vo + koff];
                const int* ui = (const int*)&u8;
                const int* vi = (const int*)&v8;
                #pragma unroll
                for (int j = 0; j < 4; ++j) {
                    h16x2 uu = __builtin_bit_cast(h16x2, ui[j]);
                    h16x2 vv = __builtin_bit_cast(h16x2, vi[j]);
                    h16x2 sum = uu + vv;
                    h16x2 lk  = __builtin_elementwise_max(sum, sum * c001);
                    o[j] = __builtin_bit_cast(int, lk);
                }
            }
            *(s16x8*)&h1L[bufi][chunk * 512 + (half * 32 + e32) * 8] = *(const s16x8*)o;
        }
    };

    build(0, 0);
    for (int tile = 0; tile < 12; ++tile) {
        __syncthreads();
        if (tile < 11) build(tile + 1, (tile + 1) & 1);
        const int buf = tile & 1;
        f32x16 acc_a, acc_b;
        #pragma unroll
        for (int r = 0; r < 16; ++r) { acc_a[r] = 0.f; acc_b[r] = 0.f; }
        __builtin_amdgcn_s_setprio(1);
        #pragma unroll
        for (int c = 0; c < 16; c += 2) {
            h16x8 b8a = __builtin_bit_cast(h16x8, *(const s16x8*)&h1L[buf][c * 512 + lane * 8]);
            h16x8 b8b = __builtin_bit_cast(h16x8, *(const s16x8*)&h1L[buf][(c + 1) * 512 + lane * 8]);
            h16x8 a8a = __builtin_bit_cast(h16x8, wa[c]);
            h16x8 a8b = __builtin_bit_cast(h16x8, wa[c + 1]);
            acc_a = __builtin_amdgcn_mfma_f32_32x32x16_f16(a8a, b8a, acc_a, 0, 0, 0);
            acc_b = __builtin_amdgcn_mfma_f32_32x32x16_f16(a8b, b8b, acc_b, 0, 0, 0);
        }
        __builtin_amdgcn_s_setprio(0);
        // in-lane epilogue: lane&31 = edge; regs r: n = w*32 + 4hf + 8g + i
        int bt = (tile >= 6) ? 1 : 0;
        int col0 = (tile - bt * 6) * 32;
        float pmu = 0.f, psg = 0.f;
        const int nsb = w * 32 + 4 * hf;
        #pragma unroll
        for (int g = 0; g < 4; ++g) {
            f32x4 b4 = *(const f32x4*)&b2L[nsb + 8 * g];     // 1x ds_read_b128
            i32x4 m4 = *(const i32x4*)&msL[nsb + 8 * g];     // 1x ds_read_b128
            #pragma unroll
            for (int i = 0; i < 4; ++i) {
                float h2 = leaky(acc_a[g * 4 + i] + acc_b[g * 4 + i] + b4[i]);
                pmu += bflo(m4[i]) * h2;
                psg += bfhi(m4[i]) * h2;
            }
        }
        pmu += __shfl_xor(pmu, 32);
        psg += __shfl_xor(psg, 32);
        if (lane < 32) atomicAdd(&mu_acc[bt * 192 + col0 + l32], pmu);
        else           atomicAdd(&sg_acc[bt * 192 + col0 + l32], psg);
    }
    __syncthreads();

    // ---- final head, both batches ----
    float lpv = 0.f;
    {
        int bt = t >> 8, i = t & 255;
        if (i < EPB) {
            float mu = softplusf(mu_acc[bt * 192 + i] + mu_b[0]);
            float sd = softplusf(sg_acc[bt * 192 + i] + sig_b[0]);
            float z = noise[(size_t)(2 * b + bt) * EPB + i];
            out[(size_t)(2 * b + bt) * EPB + i] = mu + sd * z;
            lpv = -0.5f * z * z - logf(sd);
        }
    }
    #pragma unroll
    for (int off = 1; off < 64; off <<= 1) lpv += __shfl_xor(lpv, off);
    if (lane == 0) atomicAdd(&lp_acc[t >> 8], lpv);
    __syncthreads();
    if (t < 2) out[M2 + 2 * b + t] = lp_acc[t] + LP_CONST;
}

// ---------------------------------------------------------------------------
extern "C" void kernel_launch(void* const* d_in, const int* in_sizes, int n_in,
                              void* d_out, int out_size, void* d_ws, size_t ws_size,
                              hipStream_t stream)
{
    const float* state  = (const float*)d_in[0];
    const float* conv_w = (const float*)d_in[1];
    const float* conv_b = (const float*)d_in[2];
    const float* lin1_w = (const float*)d_in[3];
    const float* lin1_b = (const float*)d_in[4];
    const float* lin2_w = (const float*)d_in[5];
    const float* lin2_b = (const float*)d_in[6];
    const float* mu_w   = (const float*)d_in[7];
    const float* mu_b   = (const float*)d_in[8];
    const float* sig_w  = (const float*)d_in[9];
    const float* sig_b  = (const float*)d_in[10];
    const float* noise  = (const float*)d_in[11];
    const int*   edges  = (const int*)d_in[13];
    float* out = (float*)d_out;

    char* ws = (char*)d_ws;
    short* W2h    = (short*)ws;  ws += 65536 * 2;
    short* W1h    = (short*)ws;  ws += 65536 * 2;
    int*   cwPT   = (int*)ws;    ws += 8192 * 4;
    int*   w1sPT  = (int*)ws;    ws += 16384 * 4;
    int*   msbf   = (int*)ws;    ws += 256 * 4;

    prep_kernel<<<256, 256, 0, stream>>>(conv_w, lin1_w, lin2_w, mu_w, sig_w,
                                         W2h, W1h, cwPT, w1sPT, msbf);
    actor_kernel<<<NB / 2, 512, 0, stream>>>(state, W1h, W2h,
                                             cwPT, conv_b, w1sPT, lin1_b,
                                             lin2_b, msbf, mu_b, sig_b,
                                             noise, edges, out);
}

// Round 11
// 210.324 us; speedup vs baseline: 1.0397x; 1.0397x over previous
//
#include <hip/hip_runtime.h>

#define ACT 14
#define CC 128
#define HH 256
#define EPB 182                 // edges per batch (14*13)
#define NB 2048
#define M2 (NB*EPB)             // 372736 edge-rows
#define NS 520                  // nodeL stride in shorts
#define LP_CONST (-182.0f * 0.91893853320467274f)   // -E*0.5*ln(2pi)

typedef short s16x8 __attribute__((ext_vector_type(8)));
typedef _Float16 h16x8 __attribute__((ext_vector_type(8)));
typedef _Float16 h16x2 __attribute__((ext_vector_type(2)));
typedef float f32x2 __attribute__((ext_vector_type(2)));
typedef float f32x4 __attribute__((ext_vector_type(4)));
typedef int   i32x4 __attribute__((ext_vector_type(4)));
typedef float f32x16 __attribute__((ext_vector_type(16)));

__device__ __forceinline__ float softplusf(float x) { return x > 15.f ? x : log1pf(expf(x)); }
__device__ __forceinline__ float leaky(float x) { return fmaxf(x, 0.01f * x); }

__device__ __forceinline__ short f2bf(float f) {
    unsigned u = __float_as_uint(f);
    unsigned r = (u + 0x7fffu + ((u >> 16) & 1u)) >> 16;   // RNE
    return (short)r;
}
__device__ __forceinline__ float bflo(int m) { return __uint_as_float(((unsigned)m) << 16); }
__device__ __forceinline__ float bfhi(int m) { return __uint_as_float((unsigned)m & 0xffff0000u); }

__device__ __forceinline__ short f2h(float f) {          // scalar f16, RNE
    _Float16 h = (_Float16)f;
    return __builtin_bit_cast(short, h);
}
__device__ __forceinline__ int pk_f16(float a, float b) { // packed f16, RTZ (1 instr)
    return __builtin_bit_cast(int, __builtin_amdgcn_cvt_pkrtz(a, b));
}
__device__ __forceinline__ int pk_f16_rn(float a, float b) {
    return (int)(unsigned short)f2h(a) | ((int)f2h(b) << 16);
}
__device__ __forceinline__ float fdot2i(int a, int b, float c) {
#if __has_builtin(__builtin_amdgcn_fdot2)
    return __builtin_amdgcn_fdot2(__builtin_bit_cast(h16x2, a),
                                  __builtin_bit_cast(h16x2, b), c, false);
#else
    h16x2 av = __builtin_bit_cast(h16x2, a), bv = __builtin_bit_cast(h16x2, b);
    return c + (float)av[0] * (float)bv[0] + (float)av[1] * (float)bv[1];
#endif
}

// ---------------------------------------------------------------------------
// prep: one-time weight conversions (256 blocks x 256), fp16 tables.
// ---------------------------------------------------------------------------
__global__ __launch_bounds__(256) void prep_kernel(
    const float* __restrict__ conv_w, const float* __restrict__ lin1_w,
    const float* __restrict__ lin2_w, const float* __restrict__ mu_w,
    const float* __restrict__ sig_w,
    short* __restrict__ W2h, short* __restrict__ W1h,
    int* __restrict__ cwPT, int* __restrict__ w1sPT,
    int* __restrict__ msbf)
{
    int i = blockIdx.x * 256 + threadIdx.x;
    W2h[i] = f2h(lin2_w[i]);
    {
        int n = i >> 7, k = i & 127;
        float v = (n < 256) ? lin1_w[n * 256 + k] : lin1_w[(n - 256) * 256 + 128 + k];
        W1h[i] = f2h(v);
    }
    if (i < 8192) {                     // cwPT[j][p]
        int j = i >> 6, p = i & 63;
        cwPT[i] = pk_f16_rn(conv_w[j * 128 + 2 * p], conv_w[j * 128 + 2 * p + 1]);
    }
    if (i < 16384) {                    // w1sPT[h][p]
        int h = i >> 6, p = i & 63;
        float a0 = lin1_w[h * 256 + 2 * p]     + lin1_w[h * 256 + 128 + 2 * p];
        float a1 = lin1_w[h * 256 + 2 * p + 1] + lin1_w[h * 256 + 128 + 2 * p + 1];
        w1sPT[i] = pk_f16_rn(a0, a1);
    }
    if (i < 256) msbf[i] = (int)(unsigned short)f2bf(mu_w[i]) | ((int)f2bf(sig_w[i]) << 16);
}

// ---------------------------------------------------------------------------
// actor: TWO batches per block (1024 blocks), 512 threads = 8 waves.
// R8 structure (proven 129.6 us) + s_setprio around the MFMA cluster.
//  A : stage state f16 (aliased into h1L); ssum -> packed pairs; LDS tables.
//  A2: g via fdot2 row streams + shfl; w via fdot2 row streams.
//  B : node GEMM -> nodeL[2], 16x16x32 f16 MFMA; wa (W2 strip) hoisted.
//  C : cooperative double-buffered H1 build (frag-order, conflict-clean),
//      single 16-deep 32x32x16 f16 MFMA chain (reg budget exactly fits:
//      wa 64 + acc 16 + temps ~48 = 128 -> 2 blocks/CU; any +16 spills,
//      measured R10), packed-bf16 mu/sig epilogue, split atomics.
// ---------------------------------------------------------------------------
__global__ __launch_bounds__(512, 4) void actor_kernel(
    const float* __restrict__ state, const short* __restrict__ W1h,
    const short* __restrict__ W2h,
    const int* __restrict__ cwPT, const float* __restrict__ conv_b,
    const int* __restrict__ w1sPT, const float* __restrict__ lin1_b,
    const float* __restrict__ lin2_b, const int* __restrict__ msbf,
    const float* __restrict__ mu_b, const float* __restrict__ sig_b,
    const float* __restrict__ noise, const int* __restrict__ edges,
    float* __restrict__ out)
{
    __shared__ short h1L[2][8192];           // 32 KB; [0] front aliased below
    __shared__ short nodeL[2 * ACT * NS];    // 29120 B
    __shared__ int   ssP[2][64];             // packed ssum f16 pairs
    __shared__ int   gP[2][64];              // packed g f16 pairs
    __shared__ float wL[2][256];
    __shared__ float b2L[256];               // lin2_b (f32)
    __shared__ int   msL[256];               // packed (mu,sig) bf16 pairs
    __shared__ int2  edgeL[192];             // edge pairs (182 used)
    __shared__ float mu_acc[384], sg_acc[384];
    __shared__ float lp_acc[2];

    short* stateL = &h1L[0][0];              // 2*2560 shorts (dead before build)

    const int t = threadIdx.x, b = blockIdx.x;
    const int lane = t & 63, ln = lane & 15, q = lane >> 4;
    const int w = t >> 6;                     // wave 0..7
    const int l32 = lane & 31, hf = lane >> 5;

    // ---- phase A ----
    #pragma unroll
    for (int it = 0; it < 2; ++it) {
        int idx = it * 512 + t;
        int bt = idx >> 9, row = (idx >> 5) & 15, c4 = idx & 31;
        int kk = c4 >> 3, k8 = (c4 & 7) * 4;
        int* dst = (int*)&stateL[bt * 2560 + kk * 640 + row * 40 + k8];
        if (row < ACT) {
            f32x4 x = *(const f32x4*)(state + ((size_t)(2 * b + bt) * ACT + row) * CC + c4 * 4);
            dst[0] = pk_f16(x[0], x[1]); dst[1] = pk_f16(x[2], x[3]);
        } else { dst[0] = 0; dst[1] = 0; }
    }
    if (t < 256) {
        b2L[t] = lin2_b[t];
        msL[t] = msbf[t];
    } else {
        int i = t - 256, bt = i >> 7, c = i & 127;    // ssum, both batches
        const float* sp = state + (size_t)(2 * b + bt) * ACT * CC + c;
        float s = 0.f;
        #pragma unroll
        for (int r = 0; r < ACT; ++r) s += sp[r * CC];
        s *= (1.f / 14.f);
        float s2 = __shfl_xor(s, 1);          // partner channel (pairs in-wave)
        if (!(c & 1)) ssP[bt][c >> 1] = pk_f16(s, s2);
    }
    if (t < EPB) edgeL[t] = ((const int2*)edges)[t];
    if (t < 384) { mu_acc[t] = 0.f; sg_acc[t] = 0.f; }
    if (t < 2) lp_acc[t] = 0.f;
    __syncthreads();

    // ---- phase A2: g = relu(conv_w @ ssum + b), fdot2 row streams ----
    {
        int bt = t >> 8, r = t & 255, j = r >> 1, s = r & 1;
        const i32x4* wp = (const i32x4*)&cwPT[j * 64 + s * 32];
        const i32x4* sp4 = (const i32x4*)&ssP[bt][s * 32];
        float a0 = 0.f, a1 = 0.f, a2 = 0.f, a3 = 0.f;
        #pragma unroll
        for (int u = 0; u < 8; ++u) {
            i32x4 wv = wp[u]; i32x4 sv = sp4[u];
            a0 = fdot2i(wv[0], sv[0], a0); a1 = fdot2i(wv[1], sv[1], a1);
            a2 = fdot2i(wv[2], sv[2], a2); a3 = fdot2i(wv[3], sv[3], a3);
        }
        float a = (a0 + a1) + (a2 + a3);
        a += __shfl_xor(a, 1);                // combine k-split halves
        float gf = fmaxf(a + conv_b[j], 0.f);
        float go = __shfl_xor(gf, 2);         // neighbor j^1
        if ((r & 3) == 0) gP[bt][r >> 2] = pk_f16(gf, go);
    }
    __syncthreads();
    // ---- w = w1s @ g + lin1_b, fdot2 row streams ----
    {
        int bt = t >> 8, h = t & 255;
        const i32x4* wp = (const i32x4*)&w1sPT[h * 64];
        const i32x4* gp4 = (const i32x4*)&gP[bt][0];
        float a0 = 0.f, a1 = 0.f, a2 = 0.f, a3 = 0.f;
        #pragma unroll 8
        for (int u = 0; u < 16; ++u) {
            i32x4 wv = wp[u]; i32x4 gv = gp4[u];
            a0 = fdot2i(wv[0], gv[0], a0); a1 = fdot2i(wv[1], gv[1], a1);
            a2 = fdot2i(wv[2], gv[2], a2); a3 = fdot2i(wv[3], gv[3], a3);
        }
        wL[bt][h] = (a0 + a1) + (a2 + a3) + lin1_b[h];
    }
    __syncthreads();

    // ---- phase B: node GEMM (u = W1L@x + w | v = W1R@x), both batches ----
    f32x4 zero4 = {0.f, 0.f, 0.f, 0.f};
    f32x4 nacc[2][4];
    #pragma unroll
    for (int bt = 0; bt < 2; ++bt) {
        nacc[bt][0] = zero4; nacc[bt][1] = zero4;
        nacc[bt][2] = zero4; nacc[bt][3] = zero4;
    }
    #pragma unroll
    for (int c = 0; c < 4; ++c) {
        h16x8 a80 = __builtin_bit_cast(h16x8, *(const s16x8*)&stateL[0 * 2560 + c * 640 + ln * 40 + q * 8]);
        h16x8 a81 = __builtin_bit_cast(h16x8, *(const s16x8*)&stateL[1 * 2560 + c * 640 + ln * 40 + q * 8]);
        #pragma unroll
        for (int i = 0; i < 4; ++i) {
            int ct = w + 8 * i;               // 0..31
            h16x8 b8 = __builtin_bit_cast(h16x8, *(const s16x8*)&W1h[(size_t)(ct * 16 + ln) * CC + c * 32 + q * 8]);
            nacc[0][i] = __builtin_amdgcn_mfma_f32_16x16x32_f16(a80, b8, nacc[0][i], 0, 0, 0);
            nacc[1][i] = __builtin_amdgcn_mfma_f32_16x16x32_f16(a81, b8, nacc[1][i], 0, 0, 0);
        }
    }

    // ---- W2 strip loads issued HERE: latency hidden by nodeL writes+barrier
    s16x8 wa[16];
    #pragma unroll
    for (int c = 0; c < 16; ++c)
        wa[c] = *(const s16x8*)&W2h[(size_t)(w * 32 + l32) * HH + c * 16 + hf * 8];

    #pragma unroll
    for (int bt = 0; bt < 2; ++bt)
        #pragma unroll
        for (int i = 0; i < 4; ++i) {
            int col = (w + 8 * i) * 16 + ln;
            float wadd = (col < HH) ? wL[bt][col] : 0.f;
            #pragma unroll
            for (int rg = 0; rg < 4; ++rg) {
                int node = q * 4 + rg;
                if (node < ACT) nodeL[(bt * ACT + node) * NS + col] = f2h(nacc[bt][i][rg] + wadd);
            }
        }
    __syncthreads();   // nodeL visible; stateL now dead

    // cooperative H1 build (each element computed once), frag-order layout,
    // packed fp16 math: 3 VALU per 2 elements; edge pairs from LDS.
    const h16x2 c001 = {(_Float16)0.01f, (_Float16)0.01f};
    auto build = [&](int tile, int bufi) {
        int bt = (tile >= 6) ? 1 : 0;
        int e32 = t & 31;
        int e = (tile - bt * 6) * 32 + e32;
        bool ok = e < EPB;
        int2 p = edgeL[ok ? e : 0];
        int base = bt * ACT * NS;
        int uo = base + p.x * NS, vo = base + HH + p.y * NS;
        int sl = t >> 5;                       // 0..15
        #pragma unroll
        for (int s = 0; s < 2; ++s) {
            int slot = sl + 16 * s;            // 0..31
            int chunk = slot >> 1, half = slot & 1;
            int koff = chunk * 16 + half * 8;
            int o[4] = {0, 0, 0, 0};
            if (ok) {
                s16x8 u8 = *(const s16x8*)&nodeL[uo + koff];
                s16x8 v8 = *(const s16x8*)&nodeL[vo + koff];
                const int* ui = (const int*)&u8;
                const int* vi = (const int*)&v8;
                #pragma unroll
                for (int j = 0; j < 4; ++j) {
                    h16x2 uu = __builtin_bit_cast(h16x2, ui[j]);
                    h16x2 vv = __builtin_bit_cast(h16x2, vi[j]);
                    h16x2 sum = uu + vv;
                    h16x2 lk  = __builtin_elementwise_max(sum, sum * c001);
                    o[j] = __builtin_bit_cast(int, lk);
                }
            }
            *(s16x8*)&h1L[bufi][chunk * 512 + (half * 32 + e32) * 8] = *(const s16x8*)o;
        }
    };

    build(0, 0);
    for (int tile = 0; tile < 12; ++tile) {
        __syncthreads();
        if (tile < 11) build(tile + 1, (tile + 1) & 1);
        const int buf = tile & 1;
        f32x16 acc;
        #pragma unroll
        for (int r = 0; r < 16; ++r) acc[r] = 0.f;
        __builtin_amdgcn_s_setprio(1);
        #pragma unroll
        for (int c = 0; c < 16; ++c) {
            h16x8 b8 = __builtin_bit_cast(h16x8, *(const s16x8*)&h1L[buf][c * 512 + lane * 8]);
            h16x8 a8 = __builtin_bit_cast(h16x8, wa[c]);
            acc = __builtin_amdgcn_mfma_f32_32x32x16_f16(a8, b8, acc, 0, 0, 0);
        }
        __builtin_amdgcn_s_setprio(0);
        // in-lane epilogue: lane&31 = edge; regs r: n = w*32 + 4hf + 8g + i
        int bt = (tile >= 6) ? 1 : 0;
        int col0 = (tile - bt * 6) * 32;
        float pmu = 0.f, psg = 0.f;
        const int nsb = w * 32 + 4 * hf;
        #pragma unroll
        for (int g = 0; g < 4; ++g) {
            f32x4 b4 = *(const f32x4*)&b2L[nsb + 8 * g];     // 1x ds_read_b128
            i32x4 m4 = *(const i32x4*)&msL[nsb + 8 * g];     // 1x ds_read_b128
            #pragma unroll
            for (int i = 0; i < 4; ++i) {
                float h2 = leaky(acc[g * 4 + i] + b4[i]);
                pmu += bflo(m4[i]) * h2;
                psg += bfhi(m4[i]) * h2;
            }
        }
        pmu += __shfl_xor(pmu, 32);
        psg += __shfl_xor(psg, 32);
        if (lane < 32) atomicAdd(&mu_acc[bt * 192 + col0 + l32], pmu);
        else           atomicAdd(&sg_acc[bt * 192 + col0 + l32], psg);
    }
    __syncthreads();

    // ---- final head, both batches ----
    float lpv = 0.f;
    {
        int bt = t >> 8, i = t & 255;
        if (i < EPB) {
            float mu = softplusf(mu_acc[bt * 192 + i] + mu_b[0]);
            float sd = softplusf(sg_acc[bt * 192 + i] + sig_b[0]);
            float z = noise[(size_t)(2 * b + bt) * EPB + i];
            out[(size_t)(2 * b + bt) * EPB + i] = mu + sd * z;
            lpv = -0.5f * z * z - logf(sd);
        }
    }
    #pragma unroll
    for (int off = 1; off < 64; off <<= 1) lpv += __shfl_xor(lpv, off);
    if (lane == 0) atomicAdd(&lp_acc[t >> 8], lpv);
    __syncthreads();
    if (t < 2) out[M2 + 2 * b + t] = lp_acc[t] + LP_CONST;
}

// ---------------------------------------------------------------------------
extern "C" void kernel_launch(void* const* d_in, const int* in_sizes, int n_in,
                              void* d_out, int out_size, void* d_ws, size_t ws_size,
                              hipStream_t stream)
{
    const float* state  = (const float*)d_in[0];
    const float* conv_w = (const float*)d_in[1];
    const float* conv_b = (const float*)d_in[2];
    const float* lin1_w = (const float*)d_in[3];
    const float* lin1_b = (const float*)d_in[4];
    const float* lin2_w = (const float*)d_in[5];
    const float* lin2_b = (const float*)d_in[6];
    const float* mu_w   = (const float*)d_in[7];
    const float* mu_b   = (const float*)d_in[8];
    const float* sig_w  = (const float*)d_in[9];
    const float* sig_b  = (const float*)d_in[10];
    const float* noise  = (const float*)d_in[11];
    const int*   edges  = (const int*)d_in[13];
    float* out = (float*)d_out;

    char* ws = (char*)d_ws;
    short* W2h    = (short*)ws;  ws += 65536 * 2;
    short* W1h    = (short*)ws;  ws += 65536 * 2;
    int*   cwPT   = (int*)ws;    ws += 8192 * 4;
    int*   w1sPT  = (int*)ws;    ws += 16384 * 4;
    int*   msbf   = (int*)ws;    ws += 256 * 4;

    prep_kernel<<<256, 256, 0, stream>>>(conv_w, lin1_w, lin2_w, mu_w, sig_w,
                                         W2h, W1h, cwPT, w1sPT, msbf);
    actor_kernel<<<NB / 2, 512, 0, stream>>>(state, W1h, W2h,
                                             cwPT, conv_b, w1sPT, lin1_b,
                                             lin2_b, msbf, mu_b, sig_b,
                                             noise, edges, out);
}

// Round 14
// 198.954 us; speedup vs baseline: 1.0991x; 1.0571x over previous
//
#include <hip/hip_runtime.h>

#define ACT 14
#define CC 128
#define HH 256
#define EPB 182                 // edges per batch (14*13)
#define NB 2048
#define M2 (NB*EPB)             // 372736 edge-rows
#define NS 520                  // nodeL stride in shorts
#define LP_CONST (-182.0f * 0.91893853320467274f)   // -E*0.5*ln(2pi)

typedef short s16x8 __attribute__((ext_vector_type(8)));
typedef _Float16 h16x8 __attribute__((ext_vector_type(8)));
typedef _Float16 h16x2 __attribute__((ext_vector_type(2)));
typedef float f32x2 __attribute__((ext_vector_type(2)));
typedef float f32x4 __attribute__((ext_vector_type(4)));
typedef int   i32x4 __attribute__((ext_vector_type(4)));
typedef float f32x16 __attribute__((ext_vector_type(16)));

__device__ __forceinline__ float softplusf(float x) { return x > 15.f ? x : log1pf(expf(x)); }
__device__ __forceinline__ float leaky(float x) { return fmaxf(x, 0.01f * x); }

__device__ __forceinline__ short f2bf(float f) {
    unsigned u = __float_as_uint(f);
    unsigned r = (u + 0x7fffu + ((u >> 16) & 1u)) >> 16;   // RNE
    return (short)r;
}
__device__ __forceinline__ float bflo(int m) { return __uint_as_float(((unsigned)m) << 16); }
__device__ __forceinline__ float bfhi(int m) { return __uint_as_float((unsigned)m & 0xffff0000u); }

__device__ __forceinline__ short f2h(float f) {          // scalar f16, RNE
    _Float16 h = (_Float16)f;
    return __builtin_bit_cast(short, h);
}
__device__ __forceinline__ int pk_f16(float a, float b) { // packed f16, RTZ (1 instr)
    return __builtin_bit_cast(int, __builtin_amdgcn_cvt_pkrtz(a, b));
}
__device__ __forceinline__ int pk_f16_rn(float a, float b) {
    return (int)(unsigned short)f2h(a) | ((int)f2h(b) << 16);
}
__device__ __forceinline__ float fdot2i(int a, int b, float c) {
#if __has_builtin(__builtin_amdgcn_fdot2)
    return __builtin_amdgcn_fdot2(__builtin_bit_cast(h16x2, a),
                                  __builtin_bit_cast(h16x2, b), c, false);
#else
    h16x2 av = __builtin_bit_cast(h16x2, a), bv = __builtin_bit_cast(h16x2, b);
    return c + (float)av[0] * (float)bv[0] + (float)av[1] * (float)bv[1];
#endif
}

// ---------------------------------------------------------------------------
// prep: one-time weight conversions (256 blocks x 256), fp16 tables.
// ---------------------------------------------------------------------------
__global__ __launch_bounds__(256) void prep_kernel(
    const float* __restrict__ conv_w, const float* __restrict__ lin1_w,
    const float* __restrict__ lin2_w, const float* __restrict__ mu_w,
    const float* __restrict__ sig_w,
    short* __restrict__ W2h, short* __restrict__ W1h,
    int* __restrict__ cwPT, int* __restrict__ w1sPT,
    int* __restrict__ msbf)
{
    int i = blockIdx.x * 256 + threadIdx.x;
    W2h[i] = f2h(lin2_w[i]);
    {
        int n = i >> 7, k = i & 127;
        float v = (n < 256) ? lin1_w[n * 256 + k] : lin1_w[(n - 256) * 256 + 128 + k];
        W1h[i] = f2h(v);
    }
    if (i < 8192) {                     // cwPT[j][p]
        int j = i >> 6, p = i & 63;
        cwPT[i] = pk_f16_rn(conv_w[j * 128 + 2 * p], conv_w[j * 128 + 2 * p + 1]);
    }
    if (i < 16384) {                    // w1sPT[h][p]
        int h = i >> 6, p = i & 63;
        float a0 = lin1_w[h * 256 + 2 * p]     + lin1_w[h * 256 + 128 + 2 * p];
        float a1 = lin1_w[h * 256 + 2 * p + 1] + lin1_w[h * 256 + 128 + 2 * p + 1];
        w1sPT[i] = pk_f16_rn(a0, a1);
    }
    if (i < 256) msbf[i] = (int)(unsigned short)f2bf(mu_w[i]) | ((int)f2bf(sig_w[i]) << 16);
}

// ---------------------------------------------------------------------------
// actor: TWO batches per block (1024 blocks), 512 threads = 8 waves.
// R8 structure exactly (proven 129.6 us actor). NO setprio, NO extra acc
// chains, NO explicit prefetch — all three were measured to spill (R9-R11):
// the reg budget is exactly saturated (wa 64 + acc 16 + ~48 temps = 128).
//  A : stage state f16 (aliased into h1L); ssum -> packed pairs; LDS tables.
//  A2: g via fdot2 row streams + shfl; w via fdot2 row streams.
//  B : node GEMM -> nodeL[2], 16x16x32 f16 MFMA; wa (W2 strip) hoisted
//      between MFMA loop and nodeL writes (hidden by writes+barrier).
//  C : cooperative double-buffered H1 build (frag-order, conflict-clean),
//      single 16-deep 32x32x16 f16 MFMA chain, packed-bf16 mu/sig epilogue,
//      split-halves LDS atomics.
// ---------------------------------------------------------------------------
__global__ __launch_bounds__(512, 4) void actor_kernel(
    const float* __restrict__ state, const short* __restrict__ W1h,
    const short* __restrict__ W2h,
    const int* __restrict__ cwPT, const float* __restrict__ conv_b,
    const int* __restrict__ w1sPT, const float* __restrict__ lin1_b,
    const float* __restrict__ lin2_b, const int* __restrict__ msbf,
    const float* __restrict__ mu_b, const float* __restrict__ sig_b,
    const float* __restrict__ noise, const int* __restrict__ edges,
    float* __restrict__ out)
{
    __shared__ short h1L[2][8192];           // 32 KB; [0] front aliased below
    __shared__ short nodeL[2 * ACT * NS];    // 29120 B
    __shared__ int   ssP[2][64];             // packed ssum f16 pairs
    __shared__ int   gP[2][64];              // packed g f16 pairs
    __shared__ float wL[2][256];
    __shared__ float b2L[256];               // lin2_b (f32)
    __shared__ int   msL[256];               // packed (mu,sig) bf16 pairs
    __shared__ int2  edgeL[192];             // edge pairs (182 used)
    __shared__ float mu_acc[384], sg_acc[384];
    __shared__ float lp_acc[2];

    short* stateL = &h1L[0][0];              // 2*2560 shorts (dead before build)

    const int t = threadIdx.x, b = blockIdx.x;
    const int lane = t & 63, ln = lane & 15, q = lane >> 4;
    const int w = t >> 6;                     // wave 0..7
    const int l32 = lane & 31, hf = lane >> 5;

    // ---- phase A ----
    #pragma unroll
    for (int it = 0; it < 2; ++it) {
        int idx = it * 512 + t;
        int bt = idx >> 9, row = (idx >> 5) & 15, c4 = idx & 31;
        int kk = c4 >> 3, k8 = (c4 & 7) * 4;
        int* dst = (int*)&stateL[bt * 2560 + kk * 640 + row * 40 + k8];
        if (row < ACT) {
            f32x4 x = *(const f32x4*)(state + ((size_t)(2 * b + bt) * ACT + row) * CC + c4 * 4);
            dst[0] = pk_f16(x[0], x[1]); dst[1] = pk_f16(x[2], x[3]);
        } else { dst[0] = 0; dst[1] = 0; }
    }
    if (t < 256) {
        b2L[t] = lin2_b[t];
        msL[t] = msbf[t];
    } else {
        int i = t - 256, bt = i >> 7, c = i & 127;    // ssum, both batches
        const float* sp = state + (size_t)(2 * b + bt) * ACT * CC + c;
        float s = 0.f;
        #pragma unroll
        for (int r = 0; r < ACT; ++r) s += sp[r * CC];
        s *= (1.f / 14.f);
        float s2 = __shfl_xor(s, 1);          // partner channel (pairs in-wave)
        if (!(c & 1)) ssP[bt][c >> 1] = pk_f16(s, s2);
    }
    if (t < EPB) edgeL[t] = ((const int2*)edges)[t];
    if (t < 384) { mu_acc[t] = 0.f; sg_acc[t] = 0.f; }
    if (t < 2) lp_acc[t] = 0.f;
    __syncthreads();

    // ---- phase A2: g = relu(conv_w @ ssum + b), fdot2 row streams ----
    {
        int bt = t >> 8, r = t & 255, j = r >> 1, s = r & 1;
        const i32x4* wp = (const i32x4*)&cwPT[j * 64 + s * 32];
        const i32x4* sp4 = (const i32x4*)&ssP[bt][s * 32];
        float a0 = 0.f, a1 = 0.f, a2 = 0.f, a3 = 0.f;
        #pragma unroll
        for (int u = 0; u < 8; ++u) {
            i32x4 wv = wp[u]; i32x4 sv = sp4[u];
            a0 = fdot2i(wv[0], sv[0], a0); a1 = fdot2i(wv[1], sv[1], a1);
            a2 = fdot2i(wv[2], sv[2], a2); a3 = fdot2i(wv[3], sv[3], a3);
        }
        float a = (a0 + a1) + (a2 + a3);
        a += __shfl_xor(a, 1);                // combine k-split halves
        float gf = fmaxf(a + conv_b[j], 0.f);
        float go = __shfl_xor(gf, 2);         // neighbor j^1
        if ((r & 3) == 0) gP[bt][r >> 2] = pk_f16(gf, go);
    }
    __syncthreads();
    // ---- w = w1s @ g + lin1_b, fdot2 row streams ----
    {
        int bt = t >> 8, h = t & 255;
        const i32x4* wp = (const i32x4*)&w1sPT[h * 64];
        const i32x4* gp4 = (const i32x4*)&gP[bt][0];
        float a0 = 0.f, a1 = 0.f, a2 = 0.f, a3 = 0.f;
        #pragma unroll 8
        for (int u = 0; u < 16; ++u) {
            i32x4 wv = wp[u]; i32x4 gv = gp4[u];
            a0 = fdot2i(wv[0], gv[0], a0); a1 = fdot2i(wv[1], gv[1], a1);
            a2 = fdot2i(wv[2], gv[2], a2); a3 = fdot2i(wv[3], gv[3], a3);
        }
        wL[bt][h] = (a0 + a1) + (a2 + a3) + lin1_b[h];
    }
    __syncthreads();

    // ---- phase B: node GEMM (u = W1L@x + w | v = W1R@x), both batches ----
    f32x4 zero4 = {0.f, 0.f, 0.f, 0.f};
    f32x4 nacc[2][4];
    #pragma unroll
    for (int bt = 0; bt < 2; ++bt) {
        nacc[bt][0] = zero4; nacc[bt][1] = zero4;
        nacc[bt][2] = zero4; nacc[bt][3] = zero4;
    }
    #pragma unroll
    for (int c = 0; c < 4; ++c) {
        h16x8 a80 = __builtin_bit_cast(h16x8, *(const s16x8*)&stateL[0 * 2560 + c * 640 + ln * 40 + q * 8]);
        h16x8 a81 = __builtin_bit_cast(h16x8, *(const s16x8*)&stateL[1 * 2560 + c * 640 + ln * 40 + q * 8]);
        #pragma unroll
        for (int i = 0; i < 4; ++i) {
            int ct = w + 8 * i;               // 0..31
            h16x8 b8 = __builtin_bit_cast(h16x8, *(const s16x8*)&W1h[(size_t)(ct * 16 + ln) * CC + c * 32 + q * 8]);
            nacc[0][i] = __builtin_amdgcn_mfma_f32_16x16x32_f16(a80, b8, nacc[0][i], 0, 0, 0);
            nacc[1][i] = __builtin_amdgcn_mfma_f32_16x16x32_f16(a81, b8, nacc[1][i], 0, 0, 0);
        }
    }

    // ---- W2 strip loads issued HERE: latency hidden by nodeL writes+barrier
    s16x8 wa[16];
    #pragma unroll
    for (int c = 0; c < 16; ++c)
        wa[c] = *(const s16x8*)&W2h[(size_t)(w * 32 + l32) * HH + c * 16 + hf * 8];

    #pragma unroll
    for (int bt = 0; bt < 2; ++bt)
        #pragma unroll
        for (int i = 0; i < 4; ++i) {
            int col = (w + 8 * i) * 16 + ln;
            float wadd = (col < HH) ? wL[bt][col] : 0.f;
            #pragma unroll
            for (int rg = 0; rg < 4; ++rg) {
                int node = q * 4 + rg;
                if (node < ACT) nodeL[(bt * ACT + node) * NS + col] = f2h(nacc[bt][i][rg] + wadd);
            }
        }
    __syncthreads();   // nodeL visible; stateL now dead

    // cooperative H1 build (each element computed once), frag-order layout,
    // packed fp16 math: 3 VALU per 2 elements; edge pairs from LDS.
    const h16x2 c001 = {(_Float16)0.01f, (_Float16)0.01f};
    auto build = [&](int tile, int bufi) {
        int bt = (tile >= 6) ? 1 : 0;
        int e32 = t & 31;
        int e = (tile - bt * 6) * 32 + e32;
        bool ok = e < EPB;
        int2 p = edgeL[ok ? e : 0];
        int base = bt * ACT * NS;
        int uo = base + p.x * NS, vo = base + HH + p.y * NS;
        int sl = t >> 5;                       // 0..15
        #pragma unroll
        for (int s = 0; s < 2; ++s) {
            int slot = sl + 16 * s;            // 0..31
            int chunk = slot >> 1, half = slot & 1;
            int koff = chunk * 16 + half * 8;
            int o[4] = {0, 0, 0, 0};
            if (ok) {
                s16x8 u8 = *(const s16x8*)&nodeL[uo + koff];
                s16x8 v8 = *(const s16x8*)&nodeL[vo + koff];
                const int* ui = (const int*)&u8;
                const int* vi = (const int*)&v8;
                #pragma unroll
                for (int j = 0; j < 4; ++j) {
                    h16x2 uu = __builtin_bit_cast(h16x2, ui[j]);
                    h16x2 vv = __builtin_bit_cast(h16x2, vi[j]);
                    h16x2 sum = uu + vv;
                    h16x2 lk  = __builtin_elementwise_max(sum, sum * c001);
                    o[j] = __builtin_bit_cast(int, lk);
                }
            }
            *(s16x8*)&h1L[bufi][chunk * 512 + (half * 32 + e32) * 8] = *(const s16x8*)o;
        }
    };

    build(0, 0);
    for (int tile = 0; tile < 12; ++tile) {
        __syncthreads();
        if (tile < 11) build(tile + 1, (tile + 1) & 1);
        const int buf = tile & 1;
        f32x16 acc;
        #pragma unroll
        for (int r = 0; r < 16; ++r) acc[r] = 0.f;
        #pragma unroll
        for (int c = 0; c < 16; ++c) {
            h16x8 b8 = __builtin_bit_cast(h16x8, *(const s16x8*)&h1L[buf][c * 512 + lane * 8]);
            h16x8 a8 = __builtin_bit_cast(h16x8, wa[c]);
            acc = __builtin_amdgcn_mfma_f32_32x32x16_f16(a8, b8, acc, 0, 0, 0);
        }
        // in-lane epilogue: lane&31 = edge; regs r: n = w*32 + 4hf + 8g + i
        int bt = (tile >= 6) ? 1 : 0;
        int col0 = (tile - bt * 6) * 32;
        float pmu = 0.f, psg = 0.f;
        const int nsb = w * 32 + 4 * hf;
        #pragma unroll
        for (int g = 0; g < 4; ++g) {
            f32x4 b4 = *(const f32x4*)&b2L[nsb + 8 * g];     // 1x ds_read_b128
            i32x4 m4 = *(const i32x4*)&msL[nsb + 8 * g];     // 1x ds_read_b128
            #pragma unroll
            for (int i = 0; i < 4; ++i) {
                float h2 = leaky(acc[g * 4 + i] + b4[i]);
                pmu += bflo(m4[i]) * h2;
                psg += bfhi(m4[i]) * h2;
            }
        }
        pmu += __shfl_xor(pmu, 32);
        psg += __shfl_xor(psg, 32);
        if (lane < 32) atomicAdd(&mu_acc[bt * 192 + col0 + l32], pmu);
        else           atomicAdd(&sg_acc[bt * 192 + col0 + l32], psg);
    }
    __syncthreads();

    // ---- final head, both batches ----
    float lpv = 0.f;
    {
        int bt = t >> 8, i = t & 255;
        if (i < EPB) {
            float mu = softplusf(mu_acc[bt * 192 + i] + mu_b[0]);
            float sd = softplusf(sg_acc[bt * 192 + i] + sig_b[0]);
            float z = noise[(size_t)(2 * b + bt) * EPB + i];
            out[(size_t)(2 * b + bt) * EPB + i] = mu + sd * z;
            lpv = -0.5f * z * z - logf(sd);
        }
    }
    #pragma unroll
    for (int off = 1; off < 64; off <<= 1) lpv += __shfl_xor(lpv, off);
    if (lane == 0) atomicAdd(&lp_acc[t >> 8], lpv);
    __syncthreads();
    if (t < 2) out[M2 + 2 * b + t] = lp_acc[t] + LP_CONST;
}

// ---------------------------------------------------------------------------
extern "C" void kernel_launch(void* const* d_in, const int* in_sizes, int n_in,
                              void* d_out, int out_size, void* d_ws, size_t ws_size,
                              hipStream_t stream)
{
    const float* state  = (const float*)d_in[0];
    const float* conv_w = (const float*)d_in[1];
    const float* conv_b = (const float*)d_in[2];
    const float* lin1_w = (const float*)d_in[3];
    const float* lin1_b = (const float*)d_in[4];
    const float* lin2_w = (const float*)d_in[5];
    const float* lin2_b = (const float*)d_in[6];
    const float* mu_w   = (const float*)d_in[7];
    const float* mu_b   = (const float*)d_in[8];
    const float* sig_w  = (const float*)d_in[9];
    const float* sig_b  = (const float*)d_in[10];
    const float* noise  = (const float*)d_in[11];
    const int*   edges  = (const int*)d_in[13];
    float* out = (float*)d_out;

    char* ws = (char*)d_ws;
    short* W2h    = (short*)ws;  ws += 65536 * 2;
    short* W1h    = (short*)ws;  ws += 65536 * 2;
    int*   cwPT   = (int*)ws;    ws += 8192 * 4;
    int*   w1sPT  = (int*)ws;    ws += 16384 * 4;
    int*   msbf   = (int*)ws;    ws += 256 * 4;

    prep_kernel<<<256, 256, 0, stream>>>(conv_w, lin1_w, lin2_w, mu_w, sig_w,
                                         W2h, W1h, cwPT, w1sPT, msbf);
    actor_kernel<<<NB / 2, 512, 0, stream>>>(state, W1h, W2h,
                                             cwPT, conv_b, w1sPT, lin1_b,
                                             lin2_b, msbf, mu_b, sig_b,
                                             noise, edges, out);
}